// Round 3
// baseline (218.838 us; speedup 1.0000x reference)
//
#include <hip/hip_runtime.h>
#include <hip/hip_bf16.h>
#include <math.h>

#define NNODES 50000
#define NEDGES 800000
#define IN1 512
#define IN2 256
#define NOUT 128
#define FTOT 256   // combined feature width (two GCN branches)

typedef __attribute__((ext_vector_type(8))) short short8;
typedef __attribute__((ext_vector_type(4))) short short4v;
typedef __attribute__((ext_vector_type(8))) short frag_ab;
typedef __attribute__((ext_vector_type(4))) float frag_cd;

// ---------------- workspace layout (bytes) ----------------
#define OFF_XW      ((size_t)0)           // N*256 bf16 = 25,600,000
#define OFF_W1T     ((size_t)25600000)    // 128x512 bf16
#define OFF_W2T     ((size_t)25731072)    // 128x256 bf16
#define OFF_DEG     ((size_t)25796608)    // N int
#define OFF_DINV    ((size_t)25996672)    // N f32
#define OFF_ROWPTR  ((size_t)26196736)    // (N+1) int
#define OFF_CURSOR  ((size_t)26396800)    // N int
#define OFF_BSUM    ((size_t)26596864)    // 256 int
#define OFF_ADJ     ((size_t)26600960)    // E int

__device__ __forceinline__ short f2bf(float f) {
    union { float f; unsigned u; } x; x.f = f;
    unsigned r = x.u + 0x7fffu + ((x.u >> 16) & 1u);   // RNE
    return (short)(r >> 16);
}
__device__ __forceinline__ float bf2f(unsigned short u) {
    union { unsigned u; float f; } x; x.u = ((unsigned)u) << 16;
    return x.f;
}

// ---------------- small kernels ----------------

__global__ __launch_bounds__(256) void wcvt_kernel(const float* __restrict__ W1, const float* __restrict__ W2,
                                                   short* __restrict__ w1t, short* __restrict__ w2t) {
    int t = blockIdx.x * 256 + threadIdx.x;
    if (t < IN1 * NOUT) {
        int c = t & 127, k = t >> 7;
        w1t[c * IN1 + k] = f2bf(W1[t]);
    } else if (t < (IN1 + IN2) * NOUT) {
        int u = t - IN1 * NOUT;
        int c = u & 127, k = u >> 7;
        w2t[c * IN2 + k] = f2bf(W2[u]);
    }
}

__global__ __launch_bounds__(256) void hist_kernel(const int* __restrict__ ei, int* __restrict__ deg, int e) {
    int i = blockIdx.x * blockDim.x + threadIdx.x;
    if (i < e) atomicAdd(&deg[ei[e + i]], 1);
}

__global__ __launch_bounds__(256) void scan_part_kernel(const int* __restrict__ deg, float* __restrict__ dinv,
                                                        int* __restrict__ bsum, int n) {
    __shared__ int s[256];
    int t = threadIdx.x;
    int i = blockIdx.x * 256 + t;
    int v = (i < n) ? deg[i] : 0;
    if (i < n) dinv[i] = rsqrtf((float)(v + 1));
    s[t] = v; __syncthreads();
    #pragma unroll
    for (int off = 128; off > 0; off >>= 1) {
        if (t < off) s[t] += s[t + off];
        __syncthreads();
    }
    if (t == 0) bsum[blockIdx.x] = s[0];
}

__global__ __launch_bounds__(256) void scan_top_kernel(int* __restrict__ bsum, int nb) {
    __shared__ int s[256];
    int t = threadIdx.x;
    int v = (t < nb) ? bsum[t] : 0;
    s[t] = v; __syncthreads();
    for (int off = 1; off < 256; off <<= 1) {
        int u = (t >= off) ? s[t - off] : 0;
        __syncthreads();
        s[t] += u;
        __syncthreads();
    }
    if (t < nb) bsum[t] = s[t] - v;
}

// writes rowptr AND cursor (cursor = rowptr copy, consumed by fill's atomics)
__global__ __launch_bounds__(256) void scan_write_kernel(const int* __restrict__ deg, const int* __restrict__ bsum,
                                                         int* __restrict__ rowptr, int* __restrict__ cursor, int n) {
    __shared__ int s[256];
    int t = threadIdx.x;
    int i = blockIdx.x * 256 + t;
    int v = (i < n) ? deg[i] : 0;
    s[t] = v; __syncthreads();
    for (int off = 1; off < 256; off <<= 1) {
        int u = (t >= off) ? s[t - off] : 0;
        __syncthreads();
        s[t] += u;
        __syncthreads();
    }
    int base = bsum[blockIdx.x];
    if (i < n) { int rp = base + s[t] - v; rowptr[i] = rp; cursor[i] = rp; }
    if (i == n - 1) rowptr[n] = base + s[t];
}

__global__ __launch_bounds__(256) void fill_kernel(const int* __restrict__ ei,
                                                   int* __restrict__ cursor, int* __restrict__ adj, int e) {
    int i = blockIdx.x * blockDim.x + threadIdx.x;
    if (i < e) {
        int src = ei[i];
        int dst = ei[e + i];
        int pos = atomicAdd(&cursor[dst], 1);
        adj[pos] = src;
    }
}

// ---------------- MFMA GEMM, 2-phase pipelined ----------------
// 64x128 tile, BK=32, 4 waves (2x2: 32x64 per wave), double-buffered LDS,
// 1-deep prefetch, ONE barrier per K-step.
#define GBM 64
#define GBK 32
__global__ __launch_bounds__(256) void gemm_kernel(const float* __restrict__ x1, const float* __restrict__ x2,
                                                   const short* __restrict__ w1t, const short* __restrict__ w2t,
                                                   short* __restrict__ xw, int n) {
    const float* X; const short* Wt; int K, colOff;
    if (blockIdx.y == 0) { X = x1; Wt = w1t; K = IN1; colOff = 0; }
    else                 { X = x2; Wt = w2t; K = IN2; colOff = 128; }

    // [buf][koff(8-elem chunk)][row][8]
    __shared__ short As[2][4][64][8];    //  8 KiB
    __shared__ short Bs[2][4][128][8];   // 16 KiB

    const int t    = threadIdx.x;
    const int lane = t & 63;
    const int wave = t >> 6;
    const int wr   = wave >> 1;          // row half (32 rows)
    const int wc   = wave & 1;           // col half (64 cols)
    const int rowBase = blockIdx.x * GBM;

    frag_cd acc[2][4];
    #pragma unroll
    for (int i = 0; i < 2; ++i)
        #pragma unroll
        for (int j = 0; j < 4; ++j)
            acc[i][j] = (frag_cd){0.f, 0.f, 0.f, 0.f};

    // A staging: thread covers row t>>2, k-chunk (t&3)*8 (8 f32 -> short8 -> 1 ds_write_b128)
    const int arow = t >> 2;
    const int aq   = t & 3;
    // B staging: thread covers col t&127, k-chunks (t>>7) and (t>>7)+2 via global_load_lds
    const int bcol = t & 127;
    const int bkof = t >> 7;

    int grow = rowBase + arow; if (grow >= n) grow = n - 1;
    const float* xrow = X + (size_t)grow * K;
    const short* wrow = Wt + (size_t)bcol * K;

    const int l15 = lane & 15, kof = lane >> 4, q = lane >> 4;

    // ---- prologue: stage tile 0 into buffer 0 ----
    {
        const float4* ap = reinterpret_cast<const float4*>(xrow + aq * 8);
        float4 a0 = ap[0], a1 = ap[1];
        char* bs = (char*)&Bs[0][0][0][0];
        __builtin_amdgcn_global_load_lds((const __attribute__((address_space(1))) void*)(wrow + bkof * 8),
            (__attribute__((address_space(3))) void*)(bs + wave * 1024), 16, 0, 0);
        __builtin_amdgcn_global_load_lds((const __attribute__((address_space(1))) void*)(wrow + (bkof + 2) * 8),
            (__attribute__((address_space(3))) void*)(bs + 4096 + wave * 1024), 16, 0, 0);
        short8 p;
        p[0]=f2bf(a0.x); p[1]=f2bf(a0.y); p[2]=f2bf(a0.z); p[3]=f2bf(a0.w);
        p[4]=f2bf(a1.x); p[5]=f2bf(a1.y); p[6]=f2bf(a1.z); p[7]=f2bf(a1.w);
        *reinterpret_cast<short8*>(&As[0][aq][arow][0]) = p;
    }
    __syncthreads();

    const int nt = K / GBK;
    int cur = 0;
    for (int it = 0; it < nt; ++it) {
        const bool haveNext = (it + 1 < nt);
        float4 n0, n1;
        if (haveNext) {
            const int ktn = (it + 1) * GBK;
            // issue next B -> LDS (buffer cur^1) and next A -> regs; both overlap MFMA below
            char* bs = (char*)&Bs[cur ^ 1][0][0][0];
            __builtin_amdgcn_global_load_lds((const __attribute__((address_space(1))) void*)(wrow + ktn + bkof * 8),
                (__attribute__((address_space(3))) void*)(bs + wave * 1024), 16, 0, 0);
            __builtin_amdgcn_global_load_lds((const __attribute__((address_space(1))) void*)(wrow + ktn + (bkof + 2) * 8),
                (__attribute__((address_space(3))) void*)(bs + 4096 + wave * 1024), 16, 0, 0);
            const float4* ap = reinterpret_cast<const float4*>(xrow + ktn + aq * 8);
            n0 = ap[0]; n1 = ap[1];
        }

        frag_ab afr[2], bfr[4];
        #pragma unroll
        for (int mf = 0; mf < 2; ++mf)
            afr[mf] = *reinterpret_cast<const frag_ab*>(&As[cur][kof][wr * 32 + mf * 16 + l15][0]);
        #pragma unroll
        for (int nf = 0; nf < 4; ++nf)
            bfr[nf] = *reinterpret_cast<const frag_ab*>(&Bs[cur][kof][wc * 64 + nf * 16 + l15][0]);

        __builtin_amdgcn_s_setprio(1);
        #pragma unroll
        for (int mf = 0; mf < 2; ++mf)
            #pragma unroll
            for (int nf = 0; nf < 4; ++nf)
                acc[mf][nf] = __builtin_amdgcn_mfma_f32_16x16x32_bf16(bfr[nf], afr[mf], acc[mf][nf], 0, 0, 0);
        __builtin_amdgcn_s_setprio(0);

        if (haveNext) {
            short8 p;
            p[0]=f2bf(n0.x); p[1]=f2bf(n0.y); p[2]=f2bf(n0.z); p[3]=f2bf(n0.w);
            p[4]=f2bf(n1.x); p[5]=f2bf(n1.y); p[6]=f2bf(n1.z); p[7]=f2bf(n1.w);
            *reinterpret_cast<short8*>(&As[cur ^ 1][aq][arow][0]) = p;
        }
        __syncthreads();   // one barrier per K-step: drains ds_write + global_load_lds
        cur ^= 1;
    }

    // epilogue: lane holds row l15, cols q*4..q*4+3 of each 16x16 frag
    #pragma unroll
    for (int mf = 0; mf < 2; ++mf) {
        int orow = rowBase + wr * 32 + mf * 16 + l15;
        if (orow < n) {
            size_t rb = (size_t)orow * FTOT + colOff + wc * 64 + q * 4;
            #pragma unroll
            for (int nf = 0; nf < 4; ++nf) {
                short4v pk;
                pk[0] = f2bf(acc[mf][nf][0]); pk[1] = f2bf(acc[mf][nf][1]);
                pk[2] = f2bf(acc[mf][nf][2]); pk[3] = f2bf(acc[mf][nf][3]);
                *reinterpret_cast<short4v*>(&xw[rb + (size_t)nf * 16]) = pk;
            }
        }
    }
}

// ---------------- gather + epilogue ----------------
__global__ __launch_bounds__(256) void gather_kernel(const unsigned short* __restrict__ xw,
                                                     const int* __restrict__ rowptr,
                                                     const int* __restrict__ adj,
                                                     const float* __restrict__ dinv,
                                                     const float* __restrict__ b1,
                                                     const float* __restrict__ b2,
                                                     float* __restrict__ out, int n) {
    int wid  = (int)((blockIdx.x * (size_t)blockDim.x + threadIdx.x) >> 6);
    int lane = threadIdx.x & 63;
    if (wid >= n) return;

    const ushort4* base = reinterpret_cast<const ushort4*>(xw);
    float ax = 0.f, ay = 0.f, az = 0.f, aw = 0.f;

    int s = rowptr[wid], e = rowptr[wid + 1];
    int i = s;
    int nsrc = (i < e) ? adj[i] : 0;
    for (; i < e; ++i) {
        int src = nsrc;
        if (i + 1 < e) nsrc = adj[i + 1];
        float w = dinv[src];
        ushort4 v = base[(size_t)src * 64 + lane];
        ax = fmaf(bf2f(v.x), w, ax);
        ay = fmaf(bf2f(v.y), w, ay);
        az = fmaf(bf2f(v.z), w, az);
        aw = fmaf(bf2f(v.w), w, aw);
    }
    float di = dinv[wid];
    {
        ushort4 v = base[(size_t)wid * 64 + lane];
        ax = fmaf(bf2f(v.x), di, ax);
        ay = fmaf(bf2f(v.y), di, ay);
        az = fmaf(bf2f(v.z), di, az);
        aw = fmaf(bf2f(v.w), di, aw);
    }
    float4 bias = (lane < 32) ? reinterpret_cast<const float4*>(b1)[lane]
                              : reinterpret_cast<const float4*>(b2)[lane - 32];
    float4 v;
    v.x = fmaxf(fmaf(ax, di, bias.x), 0.f);
    v.y = fmaxf(fmaf(ay, di, bias.y), 0.f);
    v.z = fmaxf(fmaf(az, di, bias.z), 0.f);
    v.w = fmaxf(fmaf(aw, di, bias.w), 0.f);

    float4 h;
    h.x = v.x + __shfl_xor(v.x, 32);
    h.y = v.y + __shfl_xor(v.y, 32);
    h.z = v.z + __shfl_xor(v.z, 32);
    h.w = v.w + __shfl_xor(v.w, 32);

    float m = fmaxf(fmaxf(h.x, h.y), fmaxf(h.z, h.w));
    #pragma unroll
    for (int off = 1; off <= 16; off <<= 1) m = fmaxf(m, __shfl_xor(m, off));
    float ssum = __expf(h.x - m) + __expf(h.y - m) + __expf(h.z - m) + __expf(h.w - m);
    #pragma unroll
    for (int off = 1; off <= 16; off <<= 1) ssum += __shfl_xor(ssum, off);
    float lse = m + __logf(ssum);

    if (lane < 32) {
        float4 y;
        y.x = h.x - lse; y.y = h.y - lse; y.z = h.z - lse; y.w = h.w - lse;
        reinterpret_cast<float4*>(out)[(size_t)wid * 32 + lane] = y;
    }
}

// ---------------- launcher ----------------
extern "C" void kernel_launch(void* const* d_in, const int* in_sizes, int n_in,
                              void* d_out, int out_size, void* d_ws, size_t ws_size,
                              hipStream_t stream) {
    const float* x1 = (const float*)d_in[0];
    const float* x2 = (const float*)d_in[1];
    const int*   ei = (const int*)d_in[2];
    const float* W1 = (const float*)d_in[3];
    const float* b1 = (const float*)d_in[4];
    const float* W2 = (const float*)d_in[5];
    const float* b2 = (const float*)d_in[6];
    float* out = (float*)d_out;

    const int n = in_sizes[0] / IN1;       // 50000
    const int e = in_sizes[2] / 2;         // 800000

    char* ws = (char*)d_ws;
    short* xw     = (short*)(ws + OFF_XW);
    short* w1t    = (short*)(ws + OFF_W1T);
    short* w2t    = (short*)(ws + OFF_W2T);
    int*   deg    = (int*)  (ws + OFF_DEG);
    float* dinv   = (float*)(ws + OFF_DINV);
    int*   rowptr = (int*)  (ws + OFF_ROWPTR);
    int*   cursor = (int*)  (ws + OFF_CURSOR);
    int*   bsum   = (int*)  (ws + OFF_BSUM);
    int*   adj    = (int*)  (ws + OFF_ADJ);

    const int nb_n = (n + 255) / 256;      // 196
    const int nb_e = (e + 255) / 256;

    hipMemsetAsync(deg, 0, (size_t)n * sizeof(int), stream);

    wcvt_kernel<<<((IN1 + IN2) * NOUT + 255) / 256, 256, 0, stream>>>(W1, W2, w1t, w2t);
    hist_kernel<<<nb_e, 256, 0, stream>>>(ei, deg, e);
    scan_part_kernel<<<nb_n, 256, 0, stream>>>(deg, dinv, bsum, n);
    scan_top_kernel<<<1, 256, 0, stream>>>(bsum, nb_n);
    scan_write_kernel<<<nb_n, 256, 0, stream>>>(deg, bsum, rowptr, cursor, n);
    fill_kernel<<<nb_e, 256, 0, stream>>>(ei, cursor, adj, e);

    dim3 ggrid((n + GBM - 1) / GBM, 2);
    gemm_kernel<<<ggrid, 256, 0, stream>>>(x1, x2, w1t, w2t, xw, n);

    const int waves_per_block = 4;
    int gb = (n + waves_per_block - 1) / waves_per_block;
    gather_kernel<<<gb, 256, 0, stream>>>((const unsigned short*)xw, rowptr, adj, dinv, b1, b2, out, n);
}